// Round 4
// baseline (217.346 us; speedup 1.0000x reference)
//
#include <hip/hip_runtime.h>

typedef short short8 __attribute__((ext_vector_type(8)));
typedef float f32x4 __attribute__((ext_vector_type(4)));

#define NROWS 32768
#define DIM 32
#define KCODES 8192
#define EPS_REL (1.0f/4096.0f)   // flag margin 2^-12; packed-score error bound ~2^-14·norm

// ws layout (bytes) — stays within the footprint proven in earlier rounds
#define WS_EHI  0
#define WS_ELO  (512*1024)
#define WS_PART (1024*1024)
#define WS_CNT  (WS_PART + 4096)

__device__ __forceinline__ unsigned short bf16_rne(float v){
    unsigned int u = __float_as_uint(v);
    unsigned int r = (u + 0x7fffu + ((u >> 16) & 1u)) >> 16;
    return (unsigned short)r;
}
__device__ __forceinline__ float bf16_to_f(unsigned short h){
    return __uint_as_float(((unsigned int)h) << 16);
}
__device__ __forceinline__ float dot4(const float4& a, const float4& b){
    return fmaf(a.w, b.w, fmaf(a.z, b.z, fmaf(a.y, b.y, a.x * b.x)));
}

// ---------------- prep: codebook hi/lo bf16 split + zero ticket --------------
__global__ __launch_bounds__(256) void vq_prep(
    const float* __restrict__ emb,
    unsigned short* __restrict__ ehi, unsigned short* __restrict__ elo,
    int* __restrict__ cnt)
{
    int r = blockIdx.x * 256 + threadIdx.x;   // 0..8191
    if (r == 0) cnt[0] = 0;                   // output ticket
    const float* er = emb + (size_t)r * DIM;
    short8* dh = (short8*)(ehi + (size_t)r * DIM);
    short8* dl = (short8*)(elo + (size_t)r * DIM);
    #pragma unroll
    for (int i = 0; i < 4; i++){
        float4 v0 = *(const float4*)(er + i*8);
        float4 v1 = *(const float4*)(er + i*8 + 4);
        float f[8] = {v0.x, v0.y, v0.z, v0.w, v1.x, v1.y, v1.z, v1.w};
        short8 a, b;
        #pragma unroll
        for (int j = 0; j < 8; j++){
            unsigned short h = bf16_rne(f[j]);
            a[j] = (short)h;
            b[j] = (short)bf16_rne(f[j] - bf16_to_f(h));
        }
        dh[i] = a; dl[i] = b;
    }
}

// ---------------- main: MFMA argmax, packed-uint top-2 tracking --------------
// 1024 blocks = 512 row-blocks x 2 code-halves. 8 waves/block; wave w scans
// codes [half*4096 + w*512, +512) as 32 tiles of 16. 64 rows/block.
// Bias 2*norm folded into MFMA C so scores are positive (uint-orderable).
#define PROC(bhv, blv, tcs)                                                      \
  {                                                                              \
    unsigned int tcv = (unsigned int)(tcs);                                      \
    _Pragma("unroll")                                                            \
    for (int rg = 0; rg < 4; ++rg){                                              \
      f32x4 acc = __builtin_amdgcn_mfma_f32_16x16x32_bf16(ahi[rg], bhv, cbias[rg], 0, 0, 0); \
      acc = __builtin_amdgcn_mfma_f32_16x16x32_bf16(ahi[rg], blv, acc, 0, 0, 0); \
      acc = __builtin_amdgcn_mfma_f32_16x16x32_bf16(alo[rg], bhv, acc, 0, 0, 0); \
      _Pragma("unroll")                                                          \
      for (int q = 0; q < 4; ++q){                                               \
        unsigned int u = (__float_as_uint(acc[q]) & maskv) | tcv;                \
        int rr = rg * 4 + q;                                                     \
        unsigned int nv2;                                                        \
        asm("v_med3_u32 %0, %1, %2, %3" : "=v"(nv2) : "v"(u), "v"(v1[rr]), "v"(v2[rr])); \
        v2[rr] = nv2;                                                            \
        v1[rr] = (u > v1[rr]) ? u : v1[rr];                                      \
      }                                                                          \
    }                                                                            \
  }

__global__ __launch_bounds__(512, 4) void vq_main_mfma(
    const float* __restrict__ inputs,
    const unsigned short* __restrict__ ehi,
    const unsigned short* __restrict__ elo,
    unsigned int* __restrict__ qscr)   // = (u32*)out_q; 6 words in each row's span
{
    const int L = threadIdx.x & 63;
    const int w = threadIdx.x >> 6;
    const int rb    = blockIdx.x & 511;
    const int half_ = blockIdx.x >> 9;
    const int rowbase = rb * 64;

    __shared__ float snorm[64];
    __shared__ unsigned int sv1[8][64];
    __shared__ unsigned int sv2[8][64];
    __shared__ int          scol[8][64];

    // A fragments + per-row norms (all waves load the same 64 rows)
    short8 ahi[4], alo[4];
    #pragma unroll
    for (int rg = 0; rg < 4; ++rg){
        const float* xr = inputs + (size_t)(rowbase + rg*16 + (L & 15)) * DIM + (L >> 4) * 8;
        float4 p0 = *(const float4*)xr;
        float4 p1 = *(const float4*)(xr + 4);
        float f[8] = {p0.x, p0.y, p0.z, p0.w, p1.x, p1.y, p1.z, p1.w};
        short8 h, l;
        #pragma unroll
        for (int i = 0; i < 8; i++){
            unsigned short hb = bf16_rne(f[i]);
            h[i] = (short)hb;
            l[i] = (short)bf16_rne(f[i] - bf16_to_f(hb));
        }
        ahi[rg] = h; alo[rg] = l;
        float s = dot4(p0, p0) + dot4(p1, p1);
        s += __shfl_xor(s, 16, 64);
        s += __shfl_xor(s, 32, 64);
        if (w == 0 && (L >> 4) == 0) snorm[rg*16 + L] = sqrtf(s);
    }
    __syncthreads();

    f32x4 cbias[4];
    #pragma unroll
    for (int rg = 0; rg < 4; ++rg){
        #pragma unroll
        for (int q = 0; q < 4; ++q)
            cbias[rg][q] = 2.0f * snorm[rg*16 + (L >> 4)*4 + q];
    }

    unsigned int maskv = 0xFFFFFFC0u;
    asm("" : "+v"(maskv));   // pin mask in VGPR so (x & m) | t fuses to v_and_or_b32

    unsigned int v1[16], v2[16];
    #pragma unroll
    for (int r = 0; r < 16; r++){ v1[r] = 0u; v2[r] = 0u; }

    const int c0 = half_ * 4096 + w * 512;
    const unsigned short* ehp = ehi + (size_t)(c0 + (L & 15)) * DIM + (L >> 4) * 8;
    const unsigned short* elp = elo + (size_t)(c0 + (L & 15)) * DIM + (L >> 4) * 8;

    for (int t = 0; t < 32; t += 2){
        short8 b0h = *(const short8*)(ehp);
        short8 b0l = *(const short8*)(elp);
        short8 b1h = *(const short8*)(ehp + 512);
        short8 b1l = *(const short8*)(elp + 512);
        ehp += 1024; elp += 1024;
        PROC(b0h, b0l, 31 - t);
        PROC(b1h, b1l, 30 - t);
    }

    // in-register reduction over the 16 cols (lane&15), exact top-2 merge
    unsigned int p1[16];
    #pragma unroll
    for (int r = 0; r < 16; r++) p1[r] = v1[r];
    #pragma unroll
    for (int m = 1; m < 16; m <<= 1){
        #pragma unroll
        for (int r = 0; r < 16; r++){
            unsigned int ov1 = __shfl_xor(v1[r], m, 64);
            unsigned int ov2 = __shfl_xor(v2[r], m, 64);
            unsigned int mn = min(v1[r], ov1);
            v2[r] = max(max(v2[r], ov2), mn);
            v1[r] = max(v1[r], ov1);
        }
    }
    // recover winning col via ballot (lowest matching lane = lowest col = first occurrence)
    int colr[16];
    #pragma unroll
    for (int r = 0; r < 16; r++){
        unsigned long long bm = __ballot(p1[r] == v1[r]);
        unsigned int grp = (unsigned int)((bm >> ((L >> 4) << 4)) & 0xFFFFull);
        colr[r] = __ffs(grp) - 1;
    }

    if ((L & 15) == 0){
        #pragma unroll
        for (int rg = 0; rg < 4; ++rg){
            #pragma unroll
            for (int q = 0; q < 4; ++q){
                int row = rg*16 + (L >> 4)*4 + q;   // C row = (lane>>4)*4 + reg
                sv1[w][row] = v1[rg*4 + q];
                sv2[w][row] = v2[rg*4 + q];
                scol[w][row] = colr[rg*4 + q];
            }
        }
    }
    __syncthreads();

    // merge 8 wave-slices per row; write (b1, b2, k) into the row's out_q span
    if (threadIdx.x < 64){
        int r = threadIdx.x;
        unsigned int b1 = 0u, b2 = 0u; int bw = 0, bc = 0;
        #pragma unroll
        for (int s = 0; s < 8; ++s){
            unsigned int u1 = sv1[s][r];
            unsigned int u2 = sv2[s][r];
            unsigned int mn = min(b1, u1);
            b2 = max(max(b2, u2), mn);
            bool g = u1 > b1;
            if (g){ b1 = u1; bw = s; bc = scol[s][r]; }
        }
        int t = 31 - (int)(b1 & 63u);
        int k = half_*4096 + bw*512 + t*16 + bc;
        int row = rowbase + r;
        unsigned int* qs = qscr + (size_t)row * 32 + half_ * 3;
        qs[0] = b1; qs[1] = b2; qs[2] = (unsigned int)k;
    }
}

// ------- output: merge halves, flag+exact-rescan, gather, loss finalize ------
__global__ __launch_bounds__(256) void vq_output(
    const float* __restrict__ inputs, const float* __restrict__ emb,
    float* __restrict__ out_q, float* __restrict__ out_idx,
    float* __restrict__ part, int* __restrict__ ticket, float* __restrict__ out_loss)
{
    const int row = blockIdx.x * 256 + threadIdx.x;
    unsigned int* q32 = (unsigned int*)out_q;

    // read this row's candidates (before overwriting the span)
    unsigned int a1 = q32[(size_t)row*32 + 0];
    unsigned int a2 = q32[(size_t)row*32 + 1];
    unsigned int ak = q32[(size_t)row*32 + 2];
    unsigned int b1 = q32[(size_t)row*32 + 3];
    unsigned int b2 = q32[(size_t)row*32 + 4];
    unsigned int bk = q32[(size_t)row*32 + 5];

    unsigned int w1 = a1, wk = ak;          // on tie keep half 0 (lower k)
    if (b1 > a1){ w1 = b1; wk = bk; }
    unsigned int w2 = max(max(a2, b2), min(a1, b1));

    // input row + norm
    const float4* xr = (const float4*)(inputs + (size_t)row * DIM);
    float4 x0 = xr[0], x1 = xr[1], x2 = xr[2], x3 = xr[3];
    float4 x4 = xr[4], x5 = xr[5], x6 = xr[6], x7 = xr[7];
    float nrm = sqrtf(dot4(x0,x0)+dot4(x1,x1)+dot4(x2,x2)+dot4(x3,x3)
                     +dot4(x4,x4)+dot4(x5,x5)+dot4(x6,x6)+dot4(x7,x7));

    float f1 = __uint_as_float(w1 & 0xFFFFFFC0u);
    float f2 = __uint_as_float(w2 & 0xFFFFFFC0u);
    bool flag = (f1 - f2) <= nrm * EPS_REL;

    __shared__ int frows[256];
    __shared__ int corr[256];
    __shared__ int fcnt;
    if (threadIdx.x == 0) fcnt = 0;
    corr[threadIdx.x] = -1;
    __syncthreads();
    if (flag){ int p = atomicAdd(&fcnt, 1); frows[p] = row; }
    __syncthreads();

    // cooperative exact fp32 rescan for flagged rows (expected ~0.6%)
    __shared__ float sv[4]; __shared__ int si[4];
    for (int j = 0; j < fcnt; ++j){
        int rr = frows[j];
        const float4* yr = (const float4*)(inputs + (size_t)rr * DIM);
        float4 y0 = yr[0], y1 = yr[1], y2 = yr[2], y3 = yr[3];
        float4 y4 = yr[4], y5 = yr[5], y6 = yr[6], y7 = yr[7];
        float bv = -3.0e38f; int bi = 0x7fffffff;
        for (int c = threadIdx.x; c < KCODES; c += 256){
            const float4* ep = (const float4*)(emb + (size_t)c * DIM);
            float d = dot4(y0, ep[0]) + dot4(y1, ep[1]) + dot4(y2, ep[2]) + dot4(y3, ep[3])
                    + dot4(y4, ep[4]) + dot4(y5, ep[5]) + dot4(y6, ep[6]) + dot4(y7, ep[7]);
            if (d > bv || (d == bv && c < bi)){ bv = d; bi = c; }
        }
        #pragma unroll
        for (int off = 32; off; off >>= 1){
            float ov = __shfl_down(bv, off, 64);
            int   oi = __shfl_down(bi, off, 64);
            if (ov > bv || (ov == bv && oi < bi)){ bv = ov; bi = oi; }
        }
        if ((threadIdx.x & 63) == 0){ sv[threadIdx.x >> 6] = bv; si[threadIdx.x >> 6] = bi; }
        __syncthreads();
        if (threadIdx.x == 0){
            #pragma unroll
            for (int q = 1; q < 4; q++){
                if (sv[q] > bv || (sv[q] == bv && si[q] < bi)){ bv = sv[q]; bi = si[q]; }
            }
            corr[rr & 255] = bi;
        }
        __syncthreads();
    }

    int idx = (corr[threadIdx.x] >= 0) ? corr[threadIdx.x] : (int)wk;

    // gather + loss
    const float4* ep = (const float4*)(emb + (size_t)idx * DIM);
    float4* oq = (float4*)(out_q + (size_t)row * DIM);
    float s = 0.f;
    {
        float4 q, x;
        q = ep[0]; x = x0; oq[0] = q; s += (q.x-x.x)*(q.x-x.x)+(q.y-x.y)*(q.y-x.y)+(q.z-x.z)*(q.z-x.z)+(q.w-x.w)*(q.w-x.w);
        q = ep[1]; x = x1; oq[1] = q; s += (q.x-x.x)*(q.x-x.x)+(q.y-x.y)*(q.y-x.y)+(q.z-x.z)*(q.z-x.z)+(q.w-x.w)*(q.w-x.w);
        q = ep[2]; x = x2; oq[2] = q; s += (q.x-x.x)*(q.x-x.x)+(q.y-x.y)*(q.y-x.y)+(q.z-x.z)*(q.z-x.z)+(q.w-x.w)*(q.w-x.w);
        q = ep[3]; x = x3; oq[3] = q; s += (q.x-x.x)*(q.x-x.x)+(q.y-x.y)*(q.y-x.y)+(q.z-x.z)*(q.z-x.z)+(q.w-x.w)*(q.w-x.w);
        q = ep[4]; x = x4; oq[4] = q; s += (q.x-x.x)*(q.x-x.x)+(q.y-x.y)*(q.y-x.y)+(q.z-x.z)*(q.z-x.z)+(q.w-x.w)*(q.w-x.w);
        q = ep[5]; x = x5; oq[5] = q; s += (q.x-x.x)*(q.x-x.x)+(q.y-x.y)*(q.y-x.y)+(q.z-x.z)*(q.z-x.z)+(q.w-x.w)*(q.w-x.w);
        q = ep[6]; x = x6; oq[6] = q; s += (q.x-x.x)*(q.x-x.x)+(q.y-x.y)*(q.y-x.y)+(q.z-x.z)*(q.z-x.z)+(q.w-x.w)*(q.w-x.w);
        q = ep[7]; x = x7; oq[7] = q; s += (q.x-x.x)*(q.x-x.x)+(q.y-x.y)*(q.y-x.y)+(q.z-x.z)*(q.z-x.z)+(q.w-x.w)*(q.w-x.w);
    }
    out_idx[row] = (float)idx;

    #pragma unroll
    for (int off = 32; off; off >>= 1) s += __shfl_down(s, off, 64);
    __shared__ float sp[4];
    __shared__ int tkt;
    if ((threadIdx.x & 63) == 0) sp[threadIdx.x >> 6] = s;
    __syncthreads();
    if (threadIdx.x == 0){
        part[blockIdx.x] = sp[0] + sp[1] + sp[2] + sp[3];
        __threadfence();
        tkt = atomicAdd(ticket, 1);
    }
    __syncthreads();
    if (tkt == (NROWS/256) - 1 && threadIdx.x < 64){
        __threadfence();
        float t = 0.f;
        for (int i = threadIdx.x; i < NROWS/256; i += 64) t += part[i];
        #pragma unroll
        for (int off = 32; off; off >>= 1) t += __shfl_down(t, off, 64);
        if (threadIdx.x == 0) *out_loss = t * (1.0f / ((float)NROWS * (float)DIM));
    }
}

extern "C" void kernel_launch(void* const* d_in, const int* in_sizes, int n_in,
                              void* d_out, int out_size, void* d_ws, size_t ws_size,
                              hipStream_t stream) {
    const float* inputs = (const float*)d_in[0];
    const float* emb    = (const float*)d_in[1];
    float* out      = (float*)d_out;
    float* out_q    = out;                       // [32768*32]
    float* out_loss = out + (size_t)NROWS * DIM; // [1]
    float* out_idx  = out_loss + 1;              // [32768] as float

    char* ws = (char*)d_ws;
    unsigned short* ehi  = (unsigned short*)(ws + WS_EHI);
    unsigned short* elo  = (unsigned short*)(ws + WS_ELO);
    float*          part = (float*)(ws + WS_PART);
    int*            cnt  = (int*)(ws + WS_CNT);

    vq_prep     <<<dim3(KCODES/256), dim3(256), 0, stream>>>(emb, ehi, elo, cnt);
    vq_main_mfma<<<dim3(1024),       dim3(512), 0, stream>>>(inputs, ehi, elo, (unsigned int*)out_q);
    vq_output   <<<dim3(NROWS/256),  dim3(256), 0, stream>>>(inputs, emb, out_q, out_idx, part, cnt, out_loss);
}

// Round 5
// 98.764 us; speedup vs baseline: 2.2007x; 2.2007x over previous
//
#include <hip/hip_runtime.h>

typedef short short8 __attribute__((ext_vector_type(8)));
typedef float f32x4 __attribute__((ext_vector_type(4)));

#define NROWS 32768
#define DIM 32
#define KCODES 8192
#define FLAG_CAP 16384
#define EPS_REL (1.0f/4096.0f)   // flag margin 2^-12; packed-score error bound ~2^-14·norm

// ws layout (bytes)
#define WS_EHI  0
#define WS_ELO  (512*1024)
#define WS_PART (1024*1024)            // 512 floats
#define WS_CNT  (WS_PART + 4096)       // 1 int (flag count)
#define WS_LIST (WS_CNT + 64)          // FLAG_CAP ints
#define WS_CORR (WS_LIST + FLAG_CAP*4) // FLAG_CAP floats

__device__ __forceinline__ unsigned short bf16_rne(float v){
    unsigned int u = __float_as_uint(v);
    unsigned int r = (u + 0x7fffu + ((u >> 16) & 1u)) >> 16;
    return (unsigned short)r;
}
__device__ __forceinline__ float bf16_to_f(unsigned short h){
    return __uint_as_float(((unsigned int)h) << 16);
}
__device__ __forceinline__ float dot4(const float4& a, const float4& b){
    return fmaf(a.w, b.w, fmaf(a.z, b.z, fmaf(a.y, b.y, a.x * b.x)));
}

// ---------------- prep: codebook hi/lo bf16 split + zero flag count ----------
__global__ __launch_bounds__(256) void vq_prep(
    const float* __restrict__ emb,
    unsigned short* __restrict__ ehi, unsigned short* __restrict__ elo,
    int* __restrict__ cnt)
{
    int r = blockIdx.x * 256 + threadIdx.x;   // 0..8191
    if (r == 0) cnt[0] = 0;
    const float* er = emb + (size_t)r * DIM;
    short8* dh = (short8*)(ehi + (size_t)r * DIM);
    short8* dl = (short8*)(elo + (size_t)r * DIM);
    #pragma unroll
    for (int i = 0; i < 4; i++){
        float4 v0 = *(const float4*)(er + i*8);
        float4 v1 = *(const float4*)(er + i*8 + 4);
        float f[8] = {v0.x, v0.y, v0.z, v0.w, v1.x, v1.y, v1.z, v1.w};
        short8 a, b;
        #pragma unroll
        for (int j = 0; j < 8; j++){
            unsigned short h = bf16_rne(f[j]);
            a[j] = (short)h;
            b[j] = (short)bf16_rne(f[j] - bf16_to_f(h));
        }
        dh[i] = a; dl[i] = b;
    }
}

// ---------------- main: MFMA argmax + fused gather/loss epilogue -------------
// 512 blocks x 8 waves. Wave w scans codes [w*1024,(w+1)*1024) as 64 tiles of
// 16 codes. 64 rows/block. Bias 2*norm in MFMA C keeps scores positive so the
// packed (score&~63 | 63-t) uint orders correctly with first-occurrence ties.
#define PROC(bhv, blv, tcs)                                                      \
  {                                                                              \
    unsigned int tcv = (unsigned int)(tcs);                                      \
    _Pragma("unroll")                                                            \
    for (int rg = 0; rg < 4; ++rg){                                              \
      f32x4 acc = __builtin_amdgcn_mfma_f32_16x16x32_bf16(ahi[rg], bhv, cbias[rg], 0, 0, 0); \
      acc = __builtin_amdgcn_mfma_f32_16x16x32_bf16(ahi[rg], blv, acc, 0, 0, 0); \
      acc = __builtin_amdgcn_mfma_f32_16x16x32_bf16(alo[rg], bhv, acc, 0, 0, 0); \
      _Pragma("unroll")                                                          \
      for (int q = 0; q < 4; ++q){                                               \
        unsigned int u = (__float_as_uint(acc[q]) & maskv) | tcv;                \
        int rr = rg * 4 + q;                                                     \
        unsigned int nv2;                                                        \
        asm("v_med3_u32 %0, %1, %2, %3" : "=v"(nv2) : "v"(u), "v"(v1[rr]), "v"(v2[rr])); \
        v2[rr] = nv2;                                                            \
        v1[rr] = max(u, v1[rr]);                                                 \
      }                                                                          \
    }                                                                            \
  }

__global__ __launch_bounds__(512, 4) void vq_main_mfma(
    const float* __restrict__ inputs,
    const unsigned short* __restrict__ ehi,
    const unsigned short* __restrict__ elo,
    const float* __restrict__ emb,
    float* __restrict__ out_q, float* __restrict__ out_idx,
    float* __restrict__ part, int* __restrict__ cnt, int* __restrict__ list)
{
    const int L = threadIdx.x & 63;
    const int w = threadIdx.x >> 6;
    const int rowbase = blockIdx.x * 64;

    __shared__ float snorm[64];
    __shared__ unsigned int sv1[8][64];
    __shared__ unsigned int sv2[8][64];
    __shared__ int          scol[8][64];

    // A fragments + per-row norms (all waves load the same 64 rows)
    short8 ahi[4], alo[4];
    #pragma unroll
    for (int rg = 0; rg < 4; ++rg){
        const float* xr = inputs + (size_t)(rowbase + rg*16 + (L & 15)) * DIM + (L >> 4) * 8;
        float4 p0 = *(const float4*)xr;
        float4 p1 = *(const float4*)(xr + 4);
        float f[8] = {p0.x, p0.y, p0.z, p0.w, p1.x, p1.y, p1.z, p1.w};
        short8 h, l;
        #pragma unroll
        for (int i = 0; i < 8; i++){
            unsigned short hb = bf16_rne(f[i]);
            h[i] = (short)hb;
            l[i] = (short)bf16_rne(f[i] - bf16_to_f(hb));
        }
        ahi[rg] = h; alo[rg] = l;
        float s = dot4(p0, p0) + dot4(p1, p1);
        s += __shfl_xor(s, 16, 64);
        s += __shfl_xor(s, 32, 64);
        if (w == 0 && (L >> 4) == 0) snorm[rg*16 + L] = sqrtf(s);
    }
    __syncthreads();

    f32x4 cbias[4];
    #pragma unroll
    for (int rg = 0; rg < 4; ++rg){
        #pragma unroll
        for (int q = 0; q < 4; ++q)
            cbias[rg][q] = 2.0f * snorm[rg*16 + (L >> 4)*4 + q];
    }

    unsigned int maskv = 0xFFFFFFC0u;
    asm("" : "+v"(maskv));   // pin mask in VGPR so (x & m) | t fuses to v_and_or_b32

    unsigned int v1[16], v2[16];
    #pragma unroll
    for (int r = 0; r < 16; r++){ v1[r] = 0u; v2[r] = 0u; }

    const int c0 = w * 1024;
    const unsigned short* ehp = ehi + (size_t)(c0 + (L & 15)) * DIM + (L >> 4) * 8;
    const unsigned short* elp = elo + (size_t)(c0 + (L & 15)) * DIM + (L >> 4) * 8;

    for (int t = 0; t < 64; t += 2){
        short8 b0h = *(const short8*)(ehp);
        short8 b0l = *(const short8*)(elp);
        short8 b1h = *(const short8*)(ehp + 512);
        short8 b1l = *(const short8*)(elp + 512);
        ehp += 1024; elp += 1024;
        PROC(b0h, b0l, 63 - t);
        PROC(b1h, b1l, 62 - t);
    }

    // in-register reduction over the 16 cols (lane&15), exact top-2 merge
    unsigned int p1[16];
    #pragma unroll
    for (int r = 0; r < 16; r++) p1[r] = v1[r];
    #pragma unroll
    for (int m = 1; m < 16; m <<= 1){
        #pragma unroll
        for (int r = 0; r < 16; r++){
            unsigned int ov1 = __shfl_xor(v1[r], m, 64);
            unsigned int ov2 = __shfl_xor(v2[r], m, 64);
            unsigned int mn = min(v1[r], ov1);
            v2[r] = max(max(v2[r], ov2), mn);
            v1[r] = max(v1[r], ov1);
        }
    }
    // recover winning col via ballot (lowest matching lane = lowest col = first occurrence)
    int colr[16];
    #pragma unroll
    for (int r = 0; r < 16; r++){
        unsigned long long bm = __ballot(p1[r] == v1[r]);
        unsigned int grp = (unsigned int)((bm >> ((L >> 4) << 4)) & 0xFFFFull);
        colr[r] = __ffs(grp) - 1;
    }

    if ((L & 15) == 0){
        #pragma unroll
        for (int rg = 0; rg < 4; ++rg){
            #pragma unroll
            for (int q = 0; q < 4; ++q){
                int row = rg*16 + (L >> 4)*4 + q;   // C row = (lane>>4)*4 + reg
                sv1[w][row] = v1[rg*4 + q];
                sv2[w][row] = v2[rg*4 + q];
                scol[w][row] = colr[rg*4 + q];
            }
        }
    }
    __syncthreads();

    // epilogue (threads 0..63 = wave 0): merge 8 wave-slices, gather, loss, flag
    if (threadIdx.x < 64){
        int r = threadIdx.x;
        unsigned int b1 = 0u, b2 = 0u; int bw = 0, bc = 0;
        #pragma unroll
        for (int s = 0; s < 8; ++s){
            unsigned int u1 = sv1[s][r];
            unsigned int u2 = sv2[s][r];
            unsigned int mn = min(b1, u1);
            b2 = max(max(b2, u2), mn);
            bool g = u1 > b1;
            if (g){ b1 = u1; bw = s; bc = scol[s][r]; }
        }
        int t = 63 - (int)(b1 & 63u);
        int k = bw*1024 + t*16 + bc;
        int row = rowbase + r;
        out_idx[row] = (float)k;

        // gather code row, write quantized output, per-row squared error
        const float4* ep = (const float4*)(emb + (size_t)k * DIM);
        const float4* xr = (const float4*)(inputs + (size_t)row * DIM);
        float4* oq = (float4*)(out_q + (size_t)row * DIM);
        float s = 0.f;
        #pragma unroll
        for (int i = 0; i < 8; i++){
            float4 q = ep[i], x = xr[i];
            oq[i] = q;
            float dx = q.x - x.x, dy = q.y - x.y, dz = q.z - x.z, dw = q.w - x.w;
            s += dx*dx + dy*dy + dz*dz + dw*dw;
        }

        // flag near-ties for exact fp32 refinement
        float f1 = __uint_as_float(b1 & 0xFFFFFFC0u);
        float f2 = __uint_as_float(b2 & 0xFFFFFFC0u);
        if (f1 - f2 <= snorm[r] * EPS_REL){
            int pos = atomicAdd(cnt, 1);
            if (pos < FLAG_CAP) list[pos] = row;
        }

        // 64-lane reduction of the block's loss partial
        #pragma unroll
        for (int off = 32; off; off >>= 1) s += __shfl_down(s, off, 64);
        if (r == 0) part[blockIdx.x] = s;
    }
}

// ---------------- refine: exact fp32 argmax for flagged rows + patch ---------
__global__ __launch_bounds__(256) void vq_refine(
    const float* __restrict__ inputs, const float* __restrict__ emb,
    float* __restrict__ out_q, float* __restrict__ out_idx,
    const int* __restrict__ list, const int* __restrict__ cnt,
    float* __restrict__ corrd)
{
    int n = *cnt; if (n > FLAG_CAP) n = FLAG_CAP;
    __shared__ float sv[4]; __shared__ int si[4];
    __shared__ int sbi;
    for (int j = blockIdx.x; j < n; j += gridDim.x){
        int row = list[j];
        const float4* xr = (const float4*)(inputs + (size_t)row * DIM);
        float4 x0 = xr[0], x1 = xr[1], x2 = xr[2], x3 = xr[3];
        float4 x4 = xr[4], x5 = xr[5], x6 = xr[6], x7 = xr[7];
        float bv = -3.0e38f; int bi = 0x7fffffff;
        for (int c = threadIdx.x; c < KCODES; c += 256){
            const float4* ep = (const float4*)(emb + (size_t)c * DIM);
            float d = dot4(x0, ep[0]) + dot4(x1, ep[1]) + dot4(x2, ep[2]) + dot4(x3, ep[3])
                    + dot4(x4, ep[4]) + dot4(x5, ep[5]) + dot4(x6, ep[6]) + dot4(x7, ep[7]);
            if (d > bv || (d == bv && c < bi)){ bv = d; bi = c; }
        }
        #pragma unroll
        for (int off = 32; off; off >>= 1){
            float ov = __shfl_down(bv, off, 64);
            int   oi = __shfl_down(bi, off, 64);
            if (ov > bv || (ov == bv && oi < bi)){ bv = ov; bi = oi; }
        }
        if ((threadIdx.x & 63) == 0){ sv[threadIdx.x >> 6] = bv; si[threadIdx.x >> 6] = bi; }
        __syncthreads();
        if (threadIdx.x == 0){
            #pragma unroll
            for (int q = 1; q < 4; q++){
                if (sv[q] > bv || (sv[q] == bv && si[q] < bi)){ bv = sv[q]; bi = si[q]; }
            }
            sbi = bi;
        }
        __syncthreads();
        int knew = sbi;
        int kold = (int)out_idx[row];
        // lanes 0..31 of wave 0: per-element loss delta; patch row if index changed
        if (threadIdx.x < 32){
            float x  = inputs[(size_t)row * DIM + threadIdx.x];
            float en = emb[(size_t)knew * DIM + threadIdx.x];
            float eo = emb[(size_t)kold * DIM + threadIdx.x];
            float d  = (en - x)*(en - x) - (eo - x)*(eo - x);
            #pragma unroll
            for (int off = 16; off; off >>= 1) d += __shfl_down(d, off, 64);
            if (knew != kold) out_q[(size_t)row * DIM + threadIdx.x] = en;
            if (threadIdx.x == 0){
                corrd[j] = (knew != kold) ? d : 0.0f;
                if (knew != kold) out_idx[row] = (float)knew;
            }
        }
        __syncthreads();
    }
}

// ---------------- loss: sum 512 block partials + refine deltas ---------------
__global__ __launch_bounds__(256) void vq_loss(
    const float* __restrict__ part, const float* __restrict__ corrd,
    const int* __restrict__ cnt, float* __restrict__ out_loss)
{
    int n = *cnt; if (n > FLAG_CAP) n = FLAG_CAP;
    float s = 0.f;
    for (int i = threadIdx.x; i < 512; i += 256) s += part[i];
    for (int j = threadIdx.x; j < n; j += 256) s += corrd[j];
    #pragma unroll
    for (int off = 32; off; off >>= 1) s += __shfl_down(s, off, 64);
    __shared__ float sp[4];
    if ((threadIdx.x & 63) == 0) sp[threadIdx.x >> 6] = s;
    __syncthreads();
    if (threadIdx.x == 0)
        *out_loss = (sp[0] + sp[1] + sp[2] + sp[3]) * (1.0f / ((float)NROWS * (float)DIM));
}

extern "C" void kernel_launch(void* const* d_in, const int* in_sizes, int n_in,
                              void* d_out, int out_size, void* d_ws, size_t ws_size,
                              hipStream_t stream) {
    const float* inputs = (const float*)d_in[0];
    const float* emb    = (const float*)d_in[1];
    float* out      = (float*)d_out;
    float* out_q    = out;                       // [32768*32]
    float* out_loss = out + (size_t)NROWS * DIM; // [1]
    float* out_idx  = out_loss + 1;              // [32768] as float

    char* ws = (char*)d_ws;
    unsigned short* ehi   = (unsigned short*)(ws + WS_EHI);
    unsigned short* elo   = (unsigned short*)(ws + WS_ELO);
    float*          part  = (float*)(ws + WS_PART);
    int*            cnt   = (int*)(ws + WS_CNT);
    int*            list  = (int*)(ws + WS_LIST);
    float*          corrd = (float*)(ws + WS_CORR);

    vq_prep     <<<dim3(KCODES/256), dim3(256), 0, stream>>>(emb, ehi, elo, cnt);
    vq_main_mfma<<<dim3(NROWS/64),   dim3(512), 0, stream>>>(inputs, ehi, elo, emb,
                                                             out_q, out_idx, part, cnt, list);
    vq_refine   <<<dim3(256),        dim3(256), 0, stream>>>(inputs, emb, out_q, out_idx,
                                                             list, cnt, corrd);
    vq_loss     <<<dim3(1),          dim3(256), 0, stream>>>(part, corrd, cnt, out_loss);
}